// Round 4
// baseline (324.013 us; speedup 1.0000x reference)
//
#include <hip/hip_runtime.h>

#define SZ 4096
#define NT 64  // K-tiles of BK=64

typedef unsigned short u16;
typedef __attribute__((ext_vector_type(4))) float f32x4;
typedef __attribute__((ext_vector_type(8))) short bf16x8;
typedef __attribute__((ext_vector_type(8))) unsigned short u16x8;
typedef __attribute__((ext_vector_type(4))) unsigned short u16x4;

static __device__ __forceinline__ u16 f2bf(float f) {
  union { float f; unsigned u; } v;
  v.f = f;
  unsigned r = v.u + 0x7fffu + ((v.u >> 16) & 1u);
  return (u16)(r >> 16);
}

#define ASYNC_COPY16(gsrc, ldst)                                               \
  __builtin_amdgcn_global_load_lds(                                            \
      (const __attribute__((address_space(1))) unsigned int*)(gsrc),           \
      (__attribute__((address_space(3))) unsigned int*)(ldst), 16, 0, 0)

#define BARRIER() asm volatile("s_barrier" ::: "memory")
#define WAIT_LGKM0() asm volatile("s_waitcnt lgkmcnt(0)" ::: "memory")

// ---------- pre-pass: x -> bf16 (linear) and W [K][N] -> Wt bf16 [N][K] ----------
__global__ __launch_bounds__(256) void prep_kernel(const float* __restrict__ x,
                                                   const float* __restrict__ W,
                                                   u16* __restrict__ xb,
                                                   u16* __restrict__ wt) {
  __shared__ float t[64][65];
  const int b = blockIdx.x;
  const int tid = threadIdx.x;
  if (b < 8192) {
    size_t i = ((size_t)b * 256 + tid) * 8;
    f32x4 a = *(const f32x4*)(x + i);
    f32x4 c = *(const f32x4*)(x + i + 4);
    u16x8 o;
    o[0] = f2bf(a[0]); o[1] = f2bf(a[1]); o[2] = f2bf(a[2]); o[3] = f2bf(a[3]);
    o[4] = f2bf(c[0]); o[5] = f2bf(c[1]); o[6] = f2bf(c[2]); o[7] = f2bf(c[3]);
    *(u16x8*)(xb + i) = o;
  } else {
    const int id = b - 8192;
    const size_t n0 = (size_t)(id & 63) * 64;
    const size_t k0 = (size_t)(id >> 6) * 64;
    const int tr = tid >> 4, tc = tid & 15;
#pragma unroll
    for (int i = 0; i < 4; ++i) {
      int k = i * 16 + tr;
      f32x4 v = *(const f32x4*)&W[(k0 + k) * SZ + n0 + tc * 4];
      t[k][tc * 4 + 0] = v[0]; t[k][tc * 4 + 1] = v[1];
      t[k][tc * 4 + 2] = v[2]; t[k][tc * 4 + 3] = v[3];
    }
    __syncthreads();
#pragma unroll
    for (int i = 0; i < 4; ++i) {
      int n = i * 16 + tr;
      u16x4 o;
      o[0] = f2bf(t[tc * 4 + 0][n]);
      o[1] = f2bf(t[tc * 4 + 1][n]);
      o[2] = f2bf(t[tc * 4 + 2][n]);
      o[3] = f2bf(t[tc * 4 + 3][n]);
      *(u16x4*)&wt[(n0 + n) * SZ + k0 + tc * 4] = o;
    }
  }
}

// ---------- 256x256 bf16 GEMM, 8-wave, m201 geometry: [256][64] 128B rows ----------
// st_16x32 swizzle: phys_byte = logical_byte ^ (((logical_byte>>9)&1)<<5)
//   (col-bit-4 XOR row-bit-2). Applied inverse on global source, forward on ds_read.
__global__ __launch_bounds__(512, 2) void gemm_kernel(const u16* __restrict__ pA,
                                                      const u16* __restrict__ pB,
                                                      const float* __restrict__ bias,
                                                      float* __restrict__ C) {
  __shared__ u16 As[2][256 * 64];
  __shared__ u16 Bs[2][256 * 64];

  const int tid = threadIdx.x;
  const int w = tid >> 6, lane = tid & 63;
  const int wr = w >> 2, wc = w & 3;      // wave grid 2 (M) x 4 (N)
  const int ln15 = lane & 15, hi = lane >> 4;

  // XCD-aware swizzle: 256 blocks -> 8 XCD clusters of 4(by) x 8(bx) tiles
  const int bid = blockIdx.x;
  const int xcd = bid & 7, loc = bid >> 3;
  const int by = (xcd >> 1) * 4 + (loc & 3);
  const int bx = (xcd & 1) * 8 + (loc >> 2);
  const size_t m0 = (size_t)by * 256;
  const size_t n0 = (size_t)bx * 256;

  // staging: thread tid covers bytes tid*16 + j*8192 (j=0..3) of a 32KB tile slot.
  // phys o = j*8192 + tid*16: row = j*64 + (tid>>3); swizzle bit = row bit2 = (tid>>5)&1
  // -> source col elems = (tid&7)*8 ^ ((tid&32)?16:0), row unpermuted.
  const int srow = tid >> 3;                               // 0..63
  const int scol = ((tid & 7) << 3) ^ ((tid & 32) ? 16 : 0);
  const u16* aS = pA + (m0 + srow) * SZ + scol;
  const u16* bS = pB + (n0 + srow) * SZ + scol;
  const int dOff = w * 1024;                               // lane*16 added by HW

  // read-side: frag (m,kk) logical byte = (rowbase+i*16+ln15)*128 + kk*64 + hi*16;
  // row bit2 = ln15 bit2 always -> single lane-constant XOR, immediates for the rest
  const int swz = (ln15 & 4) << 3;                         // 0 or 32
  const int aoff = ((wr * 128 + ln15) * 128 + hi * 16) ^ swz;
  const int boff = ((wc * 64 + ln15) * 128 + hi * 16) ^ swz;

#define STAGE_ALL(colbase_, slot_) do {                                        \
    const u16* sa_ = aS + (colbase_);                                          \
    const u16* sb_ = bS + (colbase_);                                          \
    char* da_ = (char*)(&As[slot_][0]) + dOff;                                 \
    char* db_ = (char*)(&Bs[slot_][0]) + dOff;                                 \
    ASYNC_COPY16(sa_, da_);                                                    \
    ASYNC_COPY16(sa_ + (size_t)64 * SZ, da_ + 8192);                           \
    ASYNC_COPY16(sa_ + (size_t)128 * SZ, da_ + 16384);                         \
    ASYNC_COPY16(sa_ + (size_t)192 * SZ, da_ + 24576);                         \
    ASYNC_COPY16(sb_, db_);                                                    \
    ASYNC_COPY16(sb_ + (size_t)64 * SZ, db_ + 8192);                           \
    ASYNC_COPY16(sb_ + (size_t)128 * SZ, db_ + 16384);                         \
    ASYNC_COPY16(sb_ + (size_t)192 * SZ, db_ + 24576);                         \
  } while (0)

#define LDA4(dst_, buf_, kh_, mh_) do {                                        \
    const char* b_ = (const char*)(&As[buf_][0]) + aoff + (mh_) * 8192 + (kh_) * 64; \
    dst_[0] = *(const bf16x8*)(b_);                                            \
    dst_[1] = *(const bf16x8*)(b_ + 2048);                                     \
    dst_[2] = *(const bf16x8*)(b_ + 4096);                                     \
    dst_[3] = *(const bf16x8*)(b_ + 6144);                                     \
  } while (0)
#define LDB4(dst_, buf_, kh_) do {                                             \
    const char* b_ = (const char*)(&Bs[buf_][0]) + boff + (kh_) * 64;          \
    dst_[0] = *(const bf16x8*)(b_);                                            \
    dst_[1] = *(const bf16x8*)(b_ + 2048);                                     \
    dst_[2] = *(const bf16x8*)(b_ + 4096);                                     \
    dst_[3] = *(const bf16x8*)(b_ + 6144);                                     \
  } while (0)

#define MFMA16(mb_) do {                                                       \
    __builtin_amdgcn_s_setprio(1);                                             \
    _Pragma("unroll")                                                          \
    for (int i_ = 0; i_ < 4; ++i_)                                             \
      _Pragma("unroll")                                                        \
      for (int n_ = 0; n_ < 4; ++n_)                                           \
        acc[(mb_) + i_][n_] = __builtin_amdgcn_mfma_f32_16x16x32_bf16(         \
            af[i_], bfr[n_], acc[(mb_) + i_], 0, 0, 0);                        \
  } while (0)

  // (note: macro above must use acc[(mb_)+i_][n_] as C-in; spelled out below)
#undef MFMA16
#define MFMA16(mb_) do {                                                       \
    __builtin_amdgcn_s_setprio(1);                                             \
    _Pragma("unroll")                                                          \
    for (int i_ = 0; i_ < 4; ++i_)                                             \
      _Pragma("unroll")                                                        \
      for (int n_ = 0; n_ < 4; ++n_)                                           \
        acc[(mb_) + i_][n_] = __builtin_amdgcn_mfma_f32_16x16x32_bf16(         \
            af[i_], bfr[n_], acc[(mb_) + i_][n_], 0, 0, 0);                    \
    __builtin_amdgcn_s_setprio(0);                                             \
  } while (0)

  f32x4 acc[8][4] = {};
  bf16x8 af[4], bfr[4];

  // prologue: stage tile 0 into slot 0; full drain (nothing else outstanding)
  STAGE_ALL(0, 0);
  asm volatile("s_waitcnt vmcnt(0)" ::: "memory");
  BARRIER();

  for (int t = 0; t < NT; ++t) {
    const int buf = t & 1;

    // ---- phase 0: issue ALL of tile t+1's stages (slot buf^1 freed by t-1's end
    //      barrier), then kk0 / m0-3
    if (t + 1 < NT) STAGE_ALL((size_t)(t + 1) * 64, buf ^ 1);
    LDB4(bfr, buf, 0);
    LDA4(af, buf, 0, 0);
    BARRIER(); WAIT_LGKM0();
    MFMA16(0);
    BARRIER();

    // ---- phase 1: kk0 / m4-7 (bfr reused across the barrier)
    LDA4(af, buf, 0, 1);
    BARRIER(); WAIT_LGKM0();
    MFMA16(4);
    BARRIER();

    // ---- phase 2: kk1 / m0-3
    LDB4(bfr, buf, 1);
    LDA4(af, buf, 1, 0);
    BARRIER(); WAIT_LGKM0();
    MFMA16(0);
    BARRIER();

    // ---- phase 3: kk1 / m4-7; drain t+1's stages (>=3 phases in flight) before
    //      the end barrier that publishes slot buf^1
    LDA4(af, buf, 1, 1);
    BARRIER(); WAIT_LGKM0();
    MFMA16(4);
    if (t + 1 < NT) asm volatile("s_waitcnt vmcnt(0)" ::: "memory");
    BARRIER();
  }

  // epilogue: C/D map col=lane&15, row=(lane>>4)*4+reg
  float bv[4];
#pragma unroll
  for (int n = 0; n < 4; ++n) bv[n] = bias[n0 + wc * 64 + n * 16 + ln15];
#pragma unroll
  for (int m = 0; m < 8; ++m) {
    const size_t row0 = m0 + wr * 128 + m * 16 + hi * 4;
#pragma unroll
    for (int n = 0; n < 4; ++n) {
      const size_t col = n0 + wc * 64 + n * 16 + ln15;
#pragma unroll
      for (int r = 0; r < 4; ++r)
        C[(row0 + r) * SZ + col] = acc[m][n][r] + bv[n];
    }
  }
#undef STAGE_ALL
#undef LDA4
#undef LDB4
#undef MFMA16
}

// ---------- fallback if workspace too small ----------
__global__ __launch_bounds__(256) void gemm_fallback(const float* __restrict__ x,
                                                     const float* __restrict__ w,
                                                     const float* __restrict__ bias,
                                                     float* __restrict__ out) {
  const int col = blockIdx.x * 256 + threadIdx.x;
  const int row = blockIdx.y;
  const float* xr = x + (size_t)row * SZ;
  float s = 0.f;
  for (int i = 0; i < SZ; ++i) s = fmaf(xr[i], w[(size_t)i * SZ + col], s);
  out[(size_t)row * SZ + col] = s + bias[col];
}

extern "C" void kernel_launch(void* const* d_in, const int* in_sizes, int n_in,
                              void* d_out, int out_size, void* d_ws, size_t ws_size,
                              hipStream_t stream) {
  const float* x = (const float*)d_in[0];
  const float* w = (const float*)d_in[1];
  const float* b = (const float*)d_in[2];
  float* out = (float*)d_out;

  const size_t need = (size_t)SZ * SZ * 2 * 2;
  if (ws_size >= need) {
    u16* xb = (u16*)d_ws;
    u16* wt = xb + (size_t)SZ * SZ;
    prep_kernel<<<12288, 256, 0, stream>>>(x, w, xb, wt);
    gemm_kernel<<<256, 512, 0, stream>>>(xb, wt, b, out);
  } else {
    gemm_fallback<<<dim3(SZ / 256, SZ), 256, 0, stream>>>(x, w, b, out);
  }
}